// Round 2
// 210.313 us; speedup vs baseline: 1.3739x; 1.3739x over previous
//
#include <hip/hip_runtime.h>
#include <hip/hip_bf16.h>

#define FDIM 128
#define BROWS 32     // i1 rows per bucket: bin = i1>>5, loc = i1&31 (5-bit pack)
#define NBLK 256     // partition blocks for hist/scatter
#define NSLICE 32    // reduction slices

typedef __attribute__((ext_vector_type(8))) short short8v;
typedef __attribute__((ext_vector_type(4))) float f32x4;

// ---- bf16 helpers (manual, RNE) ----
static __device__ __forceinline__ unsigned short f2bf(float x) {
    unsigned u = __float_as_uint(x);
    unsigned r = 0x7fffu + ((u >> 16) & 1u);
    return (unsigned short)((u + r) >> 16);
}
static __device__ __forceinline__ float bf2f(unsigned short h) {
    return __uint_as_float((unsigned)h << 16);
}
static __device__ __forceinline__ float bf_lo(unsigned u) { return __uint_as_float(u << 16); }
static __device__ __forceinline__ float bf_hi(unsigned u) { return __uint_as_float(u & 0xffff0000u); }

// split fp32 -> bf16 hi + bf16 lo (hi+lo reproduces fp32 to ~2^-17 rel)
static __device__ __forceinline__ void split2(float v, short& h, short& l) {
    unsigned short hh = f2bf(v);
    h = (short)hh;
    l = (short)f2bf(v - bf2f(hh));
}

// ---- k1: G = F @ (W + W^T) via MFMA bf16 with 3-term split (fp32-grade accuracy).
// Ws is symmetric => B-operand read as Ws[col][k] from LDS rows (transpose-free).
// Block: 512 thr = 8 waves, each wave a 16-row x 128-col stripe. ----
__global__ __launch_bounds__(512, 4) void gemm_mfma(
    const float* __restrict__ Fm, const float* __restrict__ W,
    unsigned short* __restrict__ Gbf, int N) {
    __shared__ unsigned short sH[128 * 136];   // +8 bf16 pad: row stride 272B -> 2-way (free)
    __shared__ unsigned short sL[128 * 136];

    // stage Ws = W + W^T, split hi/lo  (W is 64KB, L2-hot; transposed read L1-cached)
    for (int idx = threadIdx.x; idx < 128 * 128; idx += 512) {
        int i = idx >> 7, j = idx & 127;
        float w = W[idx] + W[j * 128 + i];
        short h, l;
        split2(w, h, l);
        sH[i * 136 + j] = (unsigned short)h;
        sL[i * 136 + j] = (unsigned short)l;
    }
    __syncthreads();

    const int wid  = threadIdx.x >> 6;
    const int lane = threadIdx.x & 63;
    const int ar   = lane & 15;    // A row within 16 / B col within 16
    const int kg   = lane >> 4;    // k-subgroup: k = kg*8 + j
    const int row0 = blockIdx.x * 128 + wid * 16;
    const int gr   = row0 + ar;
    const bool rv  = gr < N;
    const float* fp = Fm + (size_t)gr * FDIM;

    f32x4 acc[8];
#pragma unroll
    for (int t = 0; t < 8; ++t) acc[t] = (f32x4){0.f, 0.f, 0.f, 0.f};

#pragma unroll
    for (int ks = 0; ks < 4; ++ks) {
        const int k0 = ks * 32 + kg * 8;
        float4 fa = make_float4(0.f, 0.f, 0.f, 0.f);
        float4 fb = make_float4(0.f, 0.f, 0.f, 0.f);
        if (rv) {
            fa = *(const float4*)(fp + k0);
            fb = *(const float4*)(fp + k0 + 4);
        }
        short8v ah, al;
        {
            short h, l;
            split2(fa.x, h, l); ah[0] = h; al[0] = l;
            split2(fa.y, h, l); ah[1] = h; al[1] = l;
            split2(fa.z, h, l); ah[2] = h; al[2] = l;
            split2(fa.w, h, l); ah[3] = h; al[3] = l;
            split2(fb.x, h, l); ah[4] = h; al[4] = l;
            split2(fb.y, h, l); ah[5] = h; al[5] = l;
            split2(fb.z, h, l); ah[6] = h; al[6] = l;
            split2(fb.w, h, l); ah[7] = h; al[7] = l;
        }
#pragma unroll
        for (int ct = 0; ct < 8; ++ct) {
            // B[k][c] = Ws[k][ct*16+ar] = Ws[ct*16+ar][k]  (symmetry) -> contiguous 16B
            const short8v bh = *(const short8v*)(sH + (ct * 16 + ar) * 136 + k0);
            const short8v bl = *(const short8v*)(sL + (ct * 16 + ar) * 136 + k0);
            acc[ct] = __builtin_amdgcn_mfma_f32_16x16x32_bf16(ah, bh, acc[ct], 0, 0, 0);
            acc[ct] = __builtin_amdgcn_mfma_f32_16x16x32_bf16(ah, bl, acc[ct], 0, 0, 0);
            acc[ct] = __builtin_amdgcn_mfma_f32_16x16x32_bf16(al, bh, acc[ct], 0, 0, 0);
        }
    }

    // D mapping (m89-verified): row = kg*4 + r, col = ar
#pragma unroll
    for (int r = 0; r < 4; ++r) {
        const int orow = row0 + kg * 4 + r;
        if (orow < N) {
#pragma unroll
            for (int ct = 0; ct < 8; ++ct)
                Gbf[(size_t)orow * FDIM + ct * 16 + ar] = f2bf(acc[ct][r]);
        }
    }
}

// ---- k2: LDS histogram per partition block -> M[k][b] (coalesced dump) ----
__global__ __launch_bounds__(256) void k_hist(const int* __restrict__ idx, int E,
                                              int nb, unsigned* __restrict__ M) {
    extern __shared__ unsigned cnt[];
    for (int i = threadIdx.x; i < nb; i += 256) cnt[i] = 0;
    __syncthreads();
    int chunk = (E + NBLK - 1) / NBLK;
    int s = blockIdx.x * chunk;
    int e_end = min(E, s + chunk);
    for (int e = s + threadIdx.x; e < e_end; e += 256) {
        int i1 = idx[E + e];
        atomicAdd(&cnt[i1 >> 5], 1u);
    }
    __syncthreads();
    for (int i = threadIdx.x; i < nb; i += 256)
        M[(size_t)blockIdx.x * nb + i] = cnt[i];
}

// ---- k3a: wave-per-bucket exclusive scan over k of M[k][b]; emits tot[b].
// Replaces the old 7-block k_btot + serial k_mscan (was massively under-parallel). ----
__global__ __launch_bounds__(256) void k_mscan2(unsigned* __restrict__ M, int nb,
                                                unsigned* __restrict__ tot) {
    int b = blockIdx.x * 4 + (threadIdx.x >> 6);
    int lane = threadIdx.x & 63;
    if (b >= nb) return;
    unsigned m0 = M[(size_t)(4 * lane + 0) * nb + b];
    unsigned m1 = M[(size_t)(4 * lane + 1) * nb + b];
    unsigned m2 = M[(size_t)(4 * lane + 2) * nb + b];
    unsigned m3 = M[(size_t)(4 * lane + 3) * nb + b];
    unsigned s = m0 + m1 + m2 + m3;
    unsigned incl = s;
#pragma unroll
    for (int d = 1; d < 64; d <<= 1) {
        unsigned u = __shfl_up(incl, d, 64);
        if (lane >= d) incl += u;
    }
    unsigned run = incl - s;   // exclusive prefix
    M[(size_t)(4 * lane + 0) * nb + b] = run; run += m0;
    M[(size_t)(4 * lane + 1) * nb + b] = run; run += m1;
    M[(size_t)(4 * lane + 2) * nb + b] = run; run += m2;
    M[(size_t)(4 * lane + 3) * nb + b] = run;
    if (lane == 63) tot[b] = incl;
}

// ---- k3b: single-block exclusive scan of tot -> bucketStart (8/thread, unrolled) ----
__global__ __launch_bounds__(256) void k_bscan(const unsigned* __restrict__ tot, int nb,
                                               unsigned* __restrict__ bucketStart) {
    __shared__ unsigned wS[4];
    int t = threadIdx.x;
    unsigned v0, v1, v2, v3, v4, v5, v6, v7;
    int b0 = t * 8;
    v0 = (b0 + 0 < nb) ? tot[b0 + 0] : 0u;
    v1 = (b0 + 1 < nb) ? tot[b0 + 1] : 0u;
    v2 = (b0 + 2 < nb) ? tot[b0 + 2] : 0u;
    v3 = (b0 + 3 < nb) ? tot[b0 + 3] : 0u;
    v4 = (b0 + 4 < nb) ? tot[b0 + 4] : 0u;
    v5 = (b0 + 5 < nb) ? tot[b0 + 5] : 0u;
    v6 = (b0 + 6 < nb) ? tot[b0 + 6] : 0u;
    v7 = (b0 + 7 < nb) ? tot[b0 + 7] : 0u;
    unsigned l0 = 0, l1 = v0, l2 = l1 + v1, l3 = l2 + v2, l4 = l3 + v3,
             l5 = l4 + v4, l6 = l5 + v5, l7 = l6 + v6;
    unsigned s = l7 + v7;
    int lane = t & 63, wid = t >> 6;
    unsigned incl = s;
    for (int d = 1; d < 64; d <<= 1) {
        unsigned u = __shfl_up(incl, d, 64);
        if (lane >= d) incl += u;
    }
    if (lane == 63) wS[wid] = incl;
    __syncthreads();
    unsigned wOff = 0;
    for (int i = 0; i < wid; ++i) wOff += wS[i];
    unsigned base = wOff + incl - s;
    if (b0 + 0 < nb) bucketStart[b0 + 0] = base + l0;
    if (b0 + 1 < nb) bucketStart[b0 + 1] = base + l1;
    if (b0 + 2 < nb) bucketStart[b0 + 2] = base + l2;
    if (b0 + 3 < nb) bucketStart[b0 + 3] = base + l3;
    if (b0 + 4 < nb) bucketStart[b0 + 4] = base + l4;
    if (b0 + 5 < nb) bucketStart[b0 + 5] = base + l5;
    if (b0 + 6 < nb) bucketStart[b0 + 6] = base + l6;
    if (b0 + 7 < nb) bucketStart[b0 + 7] = base + l7;
    if (t == 255) bucketStart[nb] = base + s;
}

// ---- k4: scatter via LDS cursors (cursor = within-bucket prefix + bucketStart) ----
__global__ __launch_bounds__(256) void k_scatter(const int* __restrict__ idx,
                                                 const int* __restrict__ mol, int E,
                                                 int nb, const unsigned* __restrict__ M,
                                                 const unsigned* __restrict__ bucketStart,
                                                 unsigned* __restrict__ sortedE) {
    extern __shared__ unsigned cur[];
    for (int i = threadIdx.x; i < nb; i += 256)
        cur[i] = M[(size_t)blockIdx.x * nb + i] + bucketStart[i];
    __syncthreads();
    int chunk = (E + NBLK - 1) / NBLK;
    int s = blockIdx.x * chunk;
    int e_end = min(E, s + chunk);
    for (int e = s + threadIdx.x; e < e_end; e += 256) {
        int i0 = idx[e];
        int i1 = idx[E + e];
        int m  = mol[e];
        int b  = i1 >> 5;
        int loc = i1 & 31;
        unsigned pos = atomicAdd(&cur[b], 1u);
        sortedE[pos] = (unsigned)i0 | ((unsigned)m << 16) | ((unsigned)loc << 26);
    }
}

// ---- k5: edge kernel. 8 waves per bucket (512 thr, 12KB LDS -> 4 blocks/CU = 32 waves/CU),
// 2-edge unroll with sortedE prefetch for 2x MLP. VGPR must stay <=64. ----
__global__ __launch_bounds__(512, 8) void edge_kernel(
    const unsigned short* __restrict__ Gbf, const float* __restrict__ Fm,
    const unsigned* __restrict__ sortedE, const unsigned* __restrict__ bucketStart,
    float* __restrict__ part, int N, int Mout) {
    __shared__ unsigned short sFrow[BROWS * FDIM];   // 8 KB
    __shared__ float smol[1024];                     // 4 KB

    int b = blockIdx.x;
    int row0 = b * BROWS;
    int nrow = min(BROWS, N - row0);
    for (int k = threadIdx.x; k < nrow * (FDIM / 4); k += 512) {
        int r = k >> 5, c = k & 31;             // c indexes float4 within row
        float4 v = ((const float4*)(Fm + (size_t)(row0 + r) * FDIM))[c];
        ushort4 o;
        o.x = f2bf(v.x); o.y = f2bf(v.y); o.z = f2bf(v.z); o.w = f2bf(v.w);
        *(ushort4*)(sFrow + r * FDIM + c * 4) = o;
    }
    for (int i = threadIdx.x; i < 1024; i += 512) smol[i] = 0.f;
    __syncthreads();

    const int s = bucketStart[b];
    const int e_end = bucketStart[b + 1];
    const int lane = threadIdx.x & 63;
    const int sub  = lane >> 4;
    const int t16  = lane & 15;
    const int off16 = t16 * 8;
    const int wid  = threadIdx.x >> 6;

    int base = s + wid * 8;
    unsigned pkA = 0u, pkB = 0u;
    if (base + sub < e_end)     pkA = sortedE[base + sub];
    if (base + 4 + sub < e_end) pkB = sortedE[base + 4 + sub];

    while (base < e_end) {
        const int nbase = base + 64;   // 8 waves x 8 edges
        unsigned npkA = 0u, npkB = 0u;
        if (nbase + sub < e_end)     npkA = sortedE[nbase + sub];
        if (nbase + 4 + sub < e_end) npkB = sortedE[nbase + 4 + sub];

        const bool vA = (base + sub) < e_end;
        const bool vB = (base + 4 + sub) < e_end;
        const int i0A = pkA & 0xffff;
        const int i0B = pkB & 0xffff;
        const uint4 gA = *(const uint4*)(Gbf + (size_t)i0A * FDIM + off16);
        const uint4 gB = *(const uint4*)(Gbf + (size_t)i0B * FDIM + off16);
        const int locA = pkA >> 26;
        const int locB = pkB >> 26;
        const uint4 fA = *(const uint4*)(sFrow + locA * FDIM + off16);
        const uint4 fB = *(const uint4*)(sFrow + locB * FDIM + off16);

        float pA, pB;
        pA = bf_lo(gA.x) * bf_lo(fA.x);
        pA = fmaf(bf_hi(gA.x), bf_hi(fA.x), pA);
        pA = fmaf(bf_lo(gA.y), bf_lo(fA.y), pA);
        pA = fmaf(bf_hi(gA.y), bf_hi(fA.y), pA);
        pA = fmaf(bf_lo(gA.z), bf_lo(fA.z), pA);
        pA = fmaf(bf_hi(gA.z), bf_hi(fA.z), pA);
        pA = fmaf(bf_lo(gA.w), bf_lo(fA.w), pA);
        pA = fmaf(bf_hi(gA.w), bf_hi(fA.w), pA);
        pB = bf_lo(gB.x) * bf_lo(fB.x);
        pB = fmaf(bf_hi(gB.x), bf_hi(fB.x), pB);
        pB = fmaf(bf_lo(gB.y), bf_lo(fB.y), pB);
        pB = fmaf(bf_hi(gB.y), bf_hi(fB.y), pB);
        pB = fmaf(bf_lo(gB.z), bf_lo(fB.z), pB);
        pB = fmaf(bf_hi(gB.z), bf_hi(fB.z), pB);
        pB = fmaf(bf_lo(gB.w), bf_lo(fB.w), pB);
        pB = fmaf(bf_hi(gB.w), bf_hi(fB.w), pB);

        pA += __shfl_xor(pA, 1, 16);
        pB += __shfl_xor(pB, 1, 16);
        pA += __shfl_xor(pA, 2, 16);
        pB += __shfl_xor(pB, 2, 16);
        pA += __shfl_xor(pA, 4, 16);
        pB += __shfl_xor(pB, 4, 16);
        pA += __shfl_xor(pA, 8, 16);
        pB += __shfl_xor(pB, 8, 16);

        if (t16 == 0) {
            if (vA) atomicAdd(&smol[(pkA >> 16) & 0x3ff], pA);
            if (vB) atomicAdd(&smol[(pkB >> 16) & 0x3ff], pB);
        }
        pkA = npkA; pkB = npkB; base = nbase;
    }
    __syncthreads();
    float* prow = part + (size_t)b * 1024;
    for (int i = threadIdx.x; i < Mout; i += 512) prow[i] = smol[i];
}

// ---- k6a: partial reduce over buckets (32 slices -> 128 blocks, was 8/32) ----
__global__ __launch_bounds__(256) void k_red1(const float* __restrict__ part, int nb,
                                              float* __restrict__ partial, int Mout) {
    int gid = blockIdx.x * 256 + threadIdx.x;     // 32768 threads
    int m = gid & 1023;
    int sl = gid >> 10;                           // 0..NSLICE-1
    int per = (nb + NSLICE - 1) / NSLICE;
    int b0 = sl * per;
    int b1 = min(nb, b0 + per);
    float s = 0.f;
    if (m < Mout) {
        for (int b = b0; b < b1; ++b) s += part[(size_t)b * 1024 + m];
    }
    partial[sl * 1024 + m] = s;
}

// ---- k6b: final reduce ----
__global__ __launch_bounds__(256) void k_red2(const float* __restrict__ partial,
                                              float* __restrict__ out, int Mout) {
    int m = blockIdx.x * 256 + threadIdx.x;
    if (m < Mout) {
        float s = 0.f;
        for (int sl = 0; sl < NSLICE; ++sl) s += partial[sl * 1024 + m];
        out[m] = s;
    }
}

extern "C" void kernel_launch(void* const* d_in, const int* in_sizes, int n_in,
                              void* d_out, int out_size, void* d_ws, size_t ws_size,
                              hipStream_t stream) {
    const float* Fm = (const float*)d_in[0];
    const float* W  = (const float*)d_in[1];
    const int* idx  = (const int*)d_in[2];
    const int* mol  = (const int*)d_in[3];
    float* out = (float*)d_out;

    const int N = in_sizes[0] / FDIM;   // 50000
    const int E = in_sizes[3];          // 1600000

    const int nb = (N + BROWS - 1) / BROWS;   // 1563 buckets

    // workspace layout (~27.3 MB)
    char* ws = (char*)d_ws;
    size_t o = 0;
    unsigned short* Gbf = (unsigned short*)(ws + o); o += ((size_t)N * FDIM * 2 + 255) & ~(size_t)255;
    unsigned* sortedE = (unsigned*)(ws + o);         o += ((size_t)E * 4 + 255) & ~(size_t)255;
    unsigned* M = (unsigned*)(ws + o);               o += ((size_t)NBLK * nb * 4 + 255) & ~(size_t)255;
    unsigned* tot = (unsigned*)(ws + o);             o += ((size_t)nb * 4 + 255) & ~(size_t)255;
    unsigned* bucketStart = (unsigned*)(ws + o);     o += ((size_t)(nb + 1) * 4 + 255) & ~(size_t)255;
    float* part = (float*)(ws + o);                  o += (size_t)nb * 1024 * sizeof(float);
    float* partial = (float*)(ws + o);               o += NSLICE * 1024 * sizeof(float);

    gemm_mfma<<<(N + 127) / 128, 512, 0, stream>>>(Fm, W, Gbf, N);

    size_t smem = (size_t)nb * 4;
    k_hist<<<NBLK, 256, smem, stream>>>(idx, E, nb, M);
    k_mscan2<<<(nb + 3) / 4, 256, 0, stream>>>(M, nb, tot);
    k_bscan<<<1, 256, 0, stream>>>(tot, nb, bucketStart);
    k_scatter<<<NBLK, 256, smem, stream>>>(idx, mol, E, nb, M, bucketStart, sortedE);

    edge_kernel<<<nb, 512, 0, stream>>>(Gbf, Fm, sortedE, bucketStart, part, N, out_size);

    k_red1<<<NSLICE * 4, 256, 0, stream>>>(part, nb, partial, out_size);
    k_red2<<<(out_size + 255) / 256, 256, 0, stream>>>(partial, out, out_size);
}